// Round 8
// baseline (250.079 us; speedup 1.0000x reference)
//
#include <hip/hip_runtime.h>
#include <math.h>

// Math reduction (EPS=1e-12 negligible for x ~ N(0,1)):
//   gain_j = logit x_j exactly; base = sum_j softplus(x_j);
//   pos = sum_{m=1, x>0} x ; best = max_{m=1} x
//   per_sample = base - (pos>0 ? pos : best);  answer = mean over rows.
//
// Round-8: persistent waves + nt loads + register double-buffer.
// 1024 blocks x 4 waves = 4096 waves, each owns 8 contiguous rows.
// Prefetch row i+1 (8 nt dwordx4) before computing row i, so ~900-cycle
// memory latency overlaps compute+reduce instead of being paid at block
// teardown (rounds 6-7's turnover structure). If this also pins at
// ~3.6 TB/s, that's the chip's read-only ceiling (copy reads at 3.15).

constexpr int B = 32768;
constexpr int C = 1000;
constexpr int BLOCKS = 1024;
constexpr int THREADS = 256;
constexpr int WAVES = BLOCKS * (THREADS / 64);   // 4096
constexpr int RPW = B / WAVES;                   // 8 rows per wave
constexpr int TAIL = 58;                         // lanes with a 4th float4

typedef float f32x4 __attribute__((ext_vector_type(4)));

__device__ __forceinline__ void elem_update(float x, float m,
                                            float& base, float& pos, float& best) {
    // softplus(x) = max(x,0) + log(1 + exp(-|x|)); x=-1e30 contributes 0
    float e  = __expf(-fabsf(x));
    float xp = fmaxf(x, 0.0f);
    base += xp + __logf(1.0f + e);
    pos  += m * xp;                       // m in {0,1}
    if (m != 0.0f) best = fmaxf(best, x);
}

__device__ __forceinline__ void vec_update(const f32x4& x, const f32x4& m,
                                           float& b, float& p, float& s) {
    elem_update(x.x, m.x, b, p, s);
    elem_update(x.y, m.y, b, p, s);
    elem_update(x.z, m.z, b, p, s);
    elem_update(x.w, m.w, b, p, s);
}

__global__ __launch_bounds__(THREADS)
void row_loss_kernel(const float* __restrict__ X,
                     const float* __restrict__ M,
                     float* __restrict__ partial) {
    const int t    = threadIdx.x;
    const int w    = t >> 6;
    const int lane = t & 63;
    const int gwave = blockIdx.x * (THREADS / 64) + w;
    const int row0  = gwave * RPW;

    f32x4 xb[2][4], mb[2][4];

#define LOAD_ROW(buf, r)                                                        \
    {                                                                           \
        const f32x4* x4 = reinterpret_cast<const f32x4*>(X + (size_t)(r) * C);  \
        const f32x4* m4 = reinterpret_cast<const f32x4*>(M + (size_t)(r) * C);  \
        xb[buf][0] = __builtin_nontemporal_load(x4 + lane);                     \
        xb[buf][1] = __builtin_nontemporal_load(x4 + lane + 64);                \
        xb[buf][2] = __builtin_nontemporal_load(x4 + lane + 128);               \
        mb[buf][0] = __builtin_nontemporal_load(m4 + lane);                     \
        mb[buf][1] = __builtin_nontemporal_load(m4 + lane + 64);                \
        mb[buf][2] = __builtin_nontemporal_load(m4 + lane + 128);               \
        if (lane < TAIL) {                                                      \
            xb[buf][3] = __builtin_nontemporal_load(x4 + lane + 192);           \
            mb[buf][3] = __builtin_nontemporal_load(m4 + lane + 192);           \
        } else {                                                                \
            xb[buf][3] = (f32x4){-1e30f, -1e30f, -1e30f, -1e30f};               \
            mb[buf][3] = (f32x4){0.f, 0.f, 0.f, 0.f};                           \
        }                                                                       \
    }

    LOAD_ROW(0, row0);

    #pragma unroll
    for (int i = 0; i < RPW; ++i) {
        if (i + 1 < RPW) LOAD_ROW((i + 1) & 1, row0 + i + 1);   // prefetch next
        const int bsel = i & 1;

        float b0 = 0.f, b1 = 0.f, b2 = 0.f, b3 = 0.f;
        float p0 = 0.f, p1 = 0.f, p2 = 0.f, p3 = 0.f;
        float s0 = -INFINITY, s1 = -INFINITY, s2 = -INFINITY, s3 = -INFINITY;

        vec_update(xb[bsel][0], mb[bsel][0], b0, p0, s0);
        vec_update(xb[bsel][1], mb[bsel][1], b1, p1, s1);
        vec_update(xb[bsel][2], mb[bsel][2], b2, p2, s2);
        vec_update(xb[bsel][3], mb[bsel][3], b3, p3, s3);

        float base = (b0 + b1) + (b2 + b3);
        float pos  = (p0 + p1) + (p2 + p3);
        float best = fmaxf(fmaxf(s0, s1), fmaxf(s2, s3));

        #pragma unroll
        for (int off = 32; off > 0; off >>= 1) {
            base += __shfl_down(base, off, 64);
            pos  += __shfl_down(pos,  off, 64);
            best  = fmaxf(best, __shfl_down(best, off, 64));
        }

        if (lane == 0)
            partial[row0 + i] = base - ((pos > 0.f) ? pos : best);
    }
#undef LOAD_ROW
}

// Stage 1: 64 blocks x 256 threads; block b reduces partial[512b .. 512b+511]
__global__ __launch_bounds__(256)
void finalize1_kernel(const float* __restrict__ partial, float* __restrict__ mid) {
    const int b = blockIdx.x;
    const int t = threadIdx.x;
    float v = partial[b * 512 + t] + partial[b * 512 + t + 256];

    #pragma unroll
    for (int off = 32; off > 0; off >>= 1)
        v += __shfl_down(v, off, 64);

    __shared__ float s[4];
    const int w    = t >> 6;
    const int lane = t & 63;
    if (lane == 0) s[w] = v;
    __syncthreads();
    if (t == 0) mid[b] = (s[0] + s[1]) + (s[2] + s[3]);
}

// Stage 2: 1 block x 64 threads; double-precision sum, mean.
__global__ __launch_bounds__(64)
void finalize2_kernel(const float* __restrict__ mid, float* __restrict__ out) {
    double v = (double)mid[threadIdx.x];
    #pragma unroll
    for (int off = 32; off > 0; off >>= 1)
        v += __shfl_down(v, off, 64);
    if (threadIdx.x == 0) out[0] = (float)(v / (double)B);
}

extern "C" void kernel_launch(void* const* d_in, const int* in_sizes, int n_in,
                              void* d_out, int out_size, void* d_ws, size_t ws_size,
                              hipStream_t stream) {
    const float* X  = (const float*)d_in[0];
    const float* M  = (const float*)d_in[1];
    float* out      = (float*)d_out;
    float* partial  = (float*)d_ws;          // 32768 floats
    float* mid      = partial + B;           // 64 floats

    row_loss_kernel<<<BLOCKS, THREADS, 0, stream>>>(X, M, partial);
    finalize1_kernel<<<64, 256, 0, stream>>>(partial, mid);
    finalize2_kernel<<<1, 64, 0, stream>>>(mid, out);
}